// Round 8
// baseline (242.234 us; speedup 1.0000x reference)
//
#include <hip/hip_runtime.h>
#include <math.h>

#define N_PTS 65536
#define M_IND 1024
#define KNN 16
#define JITTER 1e-4f

// Packed lower-triangular Su: P[i*(i+1)/2 + j], j <= i.
#define PACKED_FLOATS (M_IND * (M_IND + 1) / 2)               // 524800
#define PACKED_BYTES  ((size_t)PACKED_FLOATS * sizeof(float)) // 2,099,200 B

// ---------------------------------------------------------------------------
// Kernel A: packed Su = tril(Lu Lu^T), Lu = tril(Lu_raw,-1)+diag(exp(diag)).
// 32x32 tiles (528 blocks) x 256 threads, 2x2 outputs/thread, BK=64 with a
// TRUE LDS double buffer and ONE barrier per chunk: the compiler's
// vmcnt(0)-before-s_barrier now drains a prefetch that was issued before the
// whole FMA loop, so global latency overlaps compute instead of sitting on
// each chunk's critical path (R3..R7 all had 2 barriers/chunk -> ~80 us).
// ---------------------------------------------------------------------------
#define TSU 32
#define BKSU 64
#define SU_BLOCKS 528   // 32*33/2 triangular tiles

__global__ __launch_bounds__(256) void su_kernel(const float* __restrict__ Lu_raw,
                                                 float* __restrict__ P) {
    __shared__ float As[2][TSU][BKSU + 4];   // 2 x 32 x 68 x4B = 17.4 KB
    __shared__ float Bs[2][TSU][BKSU + 4];

    int bid = blockIdx.x;
    int rt = (int)((sqrtf(8.0f * (float)bid + 1.0f) - 1.0f) * 0.5f);
    while ((rt + 1) * (rt + 2) / 2 <= bid) ++rt;
    while (rt * (rt + 1) / 2 > bid) --rt;
    int ct = bid - rt * (rt + 1) / 2;   // ct <= rt
    int i0 = rt * TSU, j0 = ct * TSU;

    int tid = threadIdx.x;
    int tx = tid & 15, ty = tid >> 4;        // 16x16 threads, 2x2 outputs
    int sr = tid >> 3, sc = (tid & 7) << 2;  // staging: row 0..31, col 0..28 (+32)
    int gi = i0 + sr, gj = j0 + sr;
    float a00 = 0.f, a01 = 0.f, a10 = 0.f, a11 = 0.f;

    int nch = (ct + 2) >> 1;                 // chunks of 64 cover k <= j0+31

    float4 pa0, pa1, pb0, pb1;
    auto loadc = [&](int k0) {
        const float* ra = Lu_raw + (unsigned)gi * M_IND + k0 + sc;
        const float* rb = Lu_raw + (unsigned)gj * M_IND + k0 + sc;
        pa0 = *(const float4*)(ra);
        pa1 = *(const float4*)(ra + 32);
        pb0 = *(const float4*)(rb);
        pb1 = *(const float4*)(rb + 32);
    };
    auto fixup = [&](float4 v, int grow, int kbase) -> float4 {
        float q[4] = {v.x, v.y, v.z, v.w};
        #pragma unroll
        for (int u = 0; u < 4; ++u) {
            int k = kbase + u;
            q[u] = (k < grow) ? q[u] : ((k == grow) ? __expf(q[u]) : 0.0f);
        }
        return make_float4(q[0], q[1], q[2], q[3]);
    };
    auto stage = [&](int p, int k0) {
        *(float4*)&As[p][sr][sc]      = fixup(pa0, gi, k0 + sc);
        *(float4*)&As[p][sr][sc + 32] = fixup(pa1, gi, k0 + sc + 32);
        *(float4*)&Bs[p][sr][sc]      = fixup(pb0, gj, k0 + sc);
        *(float4*)&Bs[p][sr][sc + 32] = fixup(pb1, gj, k0 + sc + 32);
    };

    loadc(0);
    stage(0, 0);
    __syncthreads();

    for (int c = 0; c < nch; ++c) {
        int p = c & 1;
        bool more = (c + 1) < nch;
        if (more) loadc((c + 1) << 6);       // prefetch next chunk (in flight
                                             // across the whole FMA loop)
        #pragma unroll
        for (int kk = 0; kk < BKSU; kk += 4) {
            float4 av0 = *(const float4*)&As[p][ty][kk];
            float4 av1 = *(const float4*)&As[p][ty + 16][kk];
            float4 bv0 = *(const float4*)&Bs[p][tx][kk];
            float4 bv1 = *(const float4*)&Bs[p][tx + 16][kk];
            a00 = fmaf(av0.x, bv0.x, fmaf(av0.y, bv0.y, fmaf(av0.z, bv0.z, fmaf(av0.w, bv0.w, a00))));
            a01 = fmaf(av0.x, bv1.x, fmaf(av0.y, bv1.y, fmaf(av0.z, bv1.z, fmaf(av0.w, bv1.w, a01))));
            a10 = fmaf(av1.x, bv0.x, fmaf(av1.y, bv0.y, fmaf(av1.z, bv0.z, fmaf(av1.w, bv0.w, a10))));
            a11 = fmaf(av1.x, bv1.x, fmaf(av1.y, bv1.y, fmaf(av1.z, bv1.z, fmaf(av1.w, bv1.w, a11))));
        }
        if (more) {
            stage(1 - p, (c + 1) << 6);      // buf 1-p: everyone finished
            __syncthreads();                 // reading it before barrier c-1
        }
    }

    int ia = i0 + ty, ib = i0 + ty + 16;
    int ja = j0 + tx, jb = j0 + tx + 16;
    if (ja <= ia) P[((unsigned)ia * (ia + 1) >> 1) + ja] = a00;
    if (jb <= ia) P[((unsigned)ia * (ia + 1) >> 1) + jb] = a01;
    if (ja <= ib) P[((unsigned)ib * (ib + 1) >> 1) + ja] = a10;
    if (jb <= ib) P[((unsigned)ib * (ib + 1) >> 1) + jb] = a11;
}

// ---------------------------------------------------------------------------
// Sorting-network helpers.
// ---------------------------------------------------------------------------
__device__ __forceinline__ void ce(unsigned long long& x, unsigned long long& y) {
    unsigned long long a = x, b = y;
    bool c = a < b;
    x = c ? a : b;
    y = c ? b : a;
}
__device__ __forceinline__ void ce(float& x, float& y) {
    float a = fminf(x, y), b = fmaxf(x, y);
    x = a; y = b;
}

// Batcher odd-even mergesort, n=16, ascending.
template <typename KT>
__device__ __forceinline__ void sort16(KT* a) {
    #pragma unroll
    for (int p = 1; p < 16; p <<= 1)
        #pragma unroll
        for (int k = p; k >= 1; k >>= 1)
            #pragma unroll
            for (int j = k & (p - 1); j + k < 16; j += 2 * k)
                #pragma unroll
                for (int i = 0; i < k; ++i)
                    if (i + j + k < 16)
                        if (((i + j) / (2 * p)) == ((i + j + k) / (2 * p)))
                            ce(a[i + j], a[i + j + k]);
}

// Bitonic cleanup for 16 (input: min of two ascending seqs, reverse-paired).
template <typename KT>
__device__ __forceinline__ void cleanup16(KT* a) {
    #pragma unroll
    for (int d = 8; d >= 1; d >>= 1)
        #pragma unroll
        for (int i = 0; i < 16; ++i)
            if ((i & d) == 0) ce(a[i], a[i | d]);
}

// Identical-bits distance (used by pass 1, pass 2, read-back, and fallback).
__device__ __forceinline__ float distf(float4 z, float x0, float x1, float x2, float xq) {
    float dot = fmaf(x0, z.x, fmaf(x1, z.y, x2 * z.z));
    return fmaxf(fmaf(-2.0f, dot, xq + z.w), 0.0f);
}

// ---------------------------------------------------------------------------
// Kernel B: two-pass threshold selection + local GP solve.
// 8 subs/point (stripe = 128 candidates), 1024 blocks x 512 threads ->
// 4 blocks/CU = 8 waves/SIMD during selection (R7 had 4 -> VALUBusy 38%).
// Pass 1: 16 f32 class minima/sub, 3-round shfl merge -> Tstar = 16th of 128
// minima (provable upper bound on the true 16th-smallest). Pass 2: collect
// indices {d <= Tstar} as u16 (cap 12/sub); read back, rebuild exact u64
// keys, sort16 + 3-round merge -> exact (dist,idx) top-16. Overflow -> exact
// serial fallback (expected hits/sub ~3, P(>12) ~ 1e-5).
// ---------------------------------------------------------------------------
#define PTS_PER_BLK 64
#define QSTRIDE 25   // u64 per point row (200 B): 8 subs x 12 u16 collect, 16 u64 hand

template <bool USE_WS>
__global__ __launch_bounds__(512, 2) void vnngp_kernel(const float* __restrict__ X,
                                                       const float* __restrict__ Z,
                                                       const float* __restrict__ mu,
                                                       const float* __restrict__ P,
                                                       const float* __restrict__ Lu_raw,
                                                       float* __restrict__ out) {
    __shared__ float4 Zs[M_IND];                             // 16 KB
    __shared__ float mus[M_IND];                             // 4 KB
    __shared__ unsigned long long qb[PTS_PER_BLK * QSTRIDE]; // 12.5 KB
    int tid = threadIdx.x;
    for (int r = tid; r < M_IND; r += 512) {
        float zx = Z[r * 3 + 0], zy = Z[r * 3 + 1], zz = Z[r * 3 + 2];
        Zs[r] = make_float4(zx, zy, zz, zx * zx + zy * zy + zz * zz);
        mus[r] = mu[r];
    }
    __syncthreads();

    {
        int pt = tid >> 3, sub = tid & 7;
        int n = blockIdx.x * PTS_PER_BLK + pt;
        float x0 = X[n * 3 + 0], x1 = X[n * 3 + 1], x2 = X[n * 3 + 2];
        float xq = fmaf(x0, x0, fmaf(x1, x1, x2 * x2));
        int mbase = sub << 7;   // 128-candidate stripe
        int rot = sub;          // 8 subs -> 8 distinct b128 bank phases

        // ---- Pass 1: 16 interleaved class minima (f32) ----
        float T[16];
        #pragma unroll
        for (int j = 0; j < 16; ++j) T[j] = 3.4e38f;
        #pragma unroll 1
        for (int c = 0; c < 8; ++c) {
            int base = mbase + (c << 4);
            #pragma unroll
            for (int j = 0; j < 16; ++j) {
                int m = base + ((j + rot) & 15);
                float d = distf(Zs[m], x0, x1, x2, xq);
                T[j] = fminf(T[j], d);
            }
        }
        sort16(T);
        #pragma unroll
        for (int round = 1; round <= 4; round <<= 1) {
            float o[16];
            #pragma unroll
            for (int i = 0; i < 16; ++i) o[i] = __shfl_xor(T[i], round, 64);
            #pragma unroll
            for (int i = 0; i < 16; ++i) T[i] = fminf(T[i], o[15 - i]);
            cleanup16(T);
        }
        float Tstar = T[15];   // >= exact 16th-smallest distance of this point

        // ---- Pass 2: collect indices with d <= Tstar (u16, cap 12/sub) ----
        unsigned short* myc = ((unsigned short*)qb) + pt * (QSTRIDE * 4) + sub * 12;
        int cnt = 0;
        #pragma unroll 1
        for (int c = 0; c < 8; ++c) {
            int base = mbase + (c << 4);
            #pragma unroll
            for (int j = 0; j < 16; ++j) {
                int m = base + ((j + rot) & 15);
                float d = distf(Zs[m], x0, x1, x2, xq);
                if (d <= Tstar) {
                    if (cnt < 12) myc[cnt] = (unsigned short)m;
                    ++cnt;
                }
            }
        }

        int ovf = cnt > 12 ? 1 : 0;
        ovf |= __shfl_xor(ovf, 1, 64);
        ovf |= __shfl_xor(ovf, 2, 64);
        ovf |= __shfl_xor(ovf, 4, 64);

        if (!ovf) {
            // read back own 12 u16 (3 x u64), rebuild exact u64 keys
            const unsigned long long* m64 = (const unsigned long long*)myc;
            unsigned long long raw[3] = {m64[0], m64[1], m64[2]};
            unsigned long long C[16];
            #pragma unroll
            for (int i = 0; i < 16; ++i) {
                int m = (i < 12) ? (int)((raw[i >> 2] >> ((i & 3) * 16)) & 0x3FF) : 0;
                float d = distf(Zs[m], x0, x1, x2, xq);
                unsigned long long key =
                    ((unsigned long long)__float_as_uint(d) << 32) | (unsigned)m;
                C[i] = (i < cnt) ? key : ~0ULL;
            }
            sort16(C);
            #pragma unroll
            for (int round = 1; round <= 4; round <<= 1) {
                unsigned long long o[16];
                #pragma unroll
                for (int i = 0; i < 16; ++i) o[i] = __shfl_xor(C[i], round, 64);
                #pragma unroll
                for (int i = 0; i < 16; ++i) {
                    unsigned long long b = o[15 - i];
                    C[i] = C[i] < b ? C[i] : b;
                }
                cleanup16(C);
            }
            if (sub == 0) {   // same-wave program order: all reads precede this
                #pragma unroll
                for (int i = 0; i < 16; ++i) qb[pt * QSTRIDE + i] = C[i];
            }
        } else if (sub == 0) {
            // Rare exact fallback: full serial scan with branchless insert.
            unsigned long long R[16];
            #pragma unroll
            for (int i = 0; i < 16; ++i) R[i] = ~0ULL;
            for (int m = 0; m < M_IND; ++m) {
                float d = distf(Zs[m], x0, x1, x2, xq);
                unsigned long long kk =
                    ((unsigned long long)__float_as_uint(d) << 32) | (unsigned)m;
                if (kk < R[15]) {
                    #pragma unroll
                    for (int j = 0; j < 16; ++j) {
                        unsigned long long t = R[j];
                        bool cc = kk < t;
                        R[j] = cc ? kk : t;
                        kk = cc ? t : kk;
                    }
                }
            }
            #pragma unroll
            for (int i = 0; i < 16; ++i) qb[pt * QSTRIDE + i] = R[i];
        }
    }
    __syncthreads();
    if (tid >= PTS_PER_BLK) return;

    // ---- Phase 2: local GP, one thread per point ----
    int n = blockIdx.x * PTS_PER_BLK + tid;
    int idx[KNN];
    float kv[KNN];
    float nx[KNN], ny[KNN], nz[KNN], nq[KNN];
    #pragma unroll
    for (int a = 0; a < KNN; ++a) {
        unsigned long long k = qb[tid * QSTRIDE + a];
        idx[a] = (int)(k & 0xFFFFFFFFULL);
        float d = __uint_as_float((unsigned)(k >> 32));
        kv[a] = __expf(-0.5f * d);            // lKxz entries
        float4 z = Zs[idx[a]];
        nx[a] = z.x; ny[a] = z.y; nz[a] = z.z; nq[a] = z.w;
    }

    // A = lKzz + JITTER*I (lower tri); lKzz diag carries global jitter from
    // Kzz_j = L L^T -> diag = 1 + 2*JITTER.
    float A[KNN * (KNN + 1) / 2];
    #pragma unroll
    for (int r = 0; r < KNN; ++r) {
        A[r * (r + 1) / 2 + r] = 1.0f + 2.0f * JITTER;
        #pragma unroll
        for (int c = 0; c < r; ++c) {
            float dd = nq[r] + nq[c]
                     - 2.0f * (nx[r] * nx[c] + ny[r] * ny[c] + nz[r] * nz[c]);
            dd = fmaxf(dd, 0.0f);
            A[r * (r + 1) / 2 + c] = __expf(-0.5f * dd);
        }
    }

    // In-place Cholesky; store 1/L[c][c] in the diagonal slot.
    #pragma unroll
    for (int c = 0; c < KNN; ++c) {
        float diag = A[c * (c + 1) / 2 + c];
        #pragma unroll
        for (int k = 0; k < c; ++k) {
            float l = A[c * (c + 1) / 2 + k];
            diag = fmaf(-l, l, diag);
        }
        float s = sqrtf(fmaxf(diag, 1e-12f));
        float rinv = 1.0f / s;
        A[c * (c + 1) / 2 + c] = rinv;
        #pragma unroll
        for (int r = c + 1; r < KNN; ++r) {
            float v = A[r * (r + 1) / 2 + c];
            #pragma unroll
            for (int k = 0; k < c; ++k)
                v = fmaf(-A[r * (r + 1) / 2 + k], A[c * (c + 1) / 2 + k], v);
            A[r * (r + 1) / 2 + c] = v * rinv;
        }
    }

    // Solve A w = kv (forward then backward).
    float w[KNN];
    #pragma unroll
    for (int r = 0; r < KNN; ++r) {
        float v = kv[r];
        #pragma unroll
        for (int c = 0; c < r; ++c) v = fmaf(-A[r * (r + 1) / 2 + c], w[c], v);
        w[r] = v * A[r * (r + 1) / 2 + r];
    }
    #pragma unroll
    for (int r = KNN - 1; r >= 0; --r) {
        float v = w[r];
        #pragma unroll
        for (int c = r + 1; c < KNN; ++c) v = fmaf(-A[c * (c + 1) / 2 + r], w[c], v);
        w[r] = v * A[r * (r + 1) / 2 + r];
    }

    // W lKzz W^T = w.k - JITTER*||w||^2   (A w = k, lKzz = A - JITTER*I)
    float wk = 0.f, ww = 0.f, mean = 0.f;
    #pragma unroll
    for (int a = 0; a < KNN; ++a) {
        wk = fmaf(w[a], kv[a], wk);
        ww = fmaf(w[a], w[a], ww);
        mean = fmaf(w[a], mus[idx[a]], mean);
    }

    // qs = w^T Su[idx,idx] w
    float qs = 0.f;
    if (USE_WS) {
        #pragma unroll
        for (int r = 0; r < KNN; ++r) {
            int a = idx[r];
            float wr = w[r];
            float rowacc = 0.f;
            #pragma unroll
            for (int c = 0; c < r; ++c) {
                int b = idx[c];
                int hi = a > b ? a : b;
                int lo = a > b ? b : a;
                rowacc = fmaf(w[c], P[((unsigned)hi * (hi + 1) >> 1) + lo], rowacc);
            }
            qs = fmaf(wr, fmaf(wr, P[((unsigned)a * (a + 1) >> 1) + a], 2.0f * rowacc), qs);
        }
    } else {
        // On-demand fallback: qs = sum_k (sum_a w_a * Lu[idx_a, k])^2
        int si[KNN]; float sw[KNN];
        #pragma unroll
        for (int a = 0; a < KNN; ++a) { si[a] = idx[a]; sw[a] = w[a]; }
        #pragma unroll
        for (int a = 1; a < KNN; ++a) {
            int iv = si[a]; float wv = sw[a];
            int b = a - 1;
            while (b >= 0 && si[b] > iv) { si[b + 1] = si[b]; sw[b + 1] = sw[b]; --b; }
            si[b + 1] = iv; sw[b + 1] = wv;
        }
        int s = 0;
        int kend = si[KNN - 1];
        for (int k = 0; k <= kend; ++k) {
            float v = 0.f;
            if (s < KNN && si[s] == k) {
                v = sw[s] * __expf(Lu_raw[(unsigned)k * M_IND + k]);
                ++s;
            }
            for (int a = s; a < KNN; ++a)
                v = fmaf(sw[a], Lu_raw[(unsigned)si[a] * M_IND + k], v);
            qs = fmaf(v, v, qs);
        }
    }

    float cov = 1.0f - (wk - JITTER * ww) + qs;
    float sd = sqrtf(fmaxf(cov, 0.05f));
    out[n] = mean;
    out[N_PTS + n] = sd;
}

// ---------------------------------------------------------------------------
extern "C" void kernel_launch(void* const* d_in, const int* in_sizes, int n_in,
                              void* d_out, int out_size, void* d_ws, size_t ws_size,
                              hipStream_t stream) {
    const float* X      = (const float*)d_in[0];
    const float* Z      = (const float*)d_in[1];
    const float* Lu_raw = (const float*)d_in[2];
    const float* mu     = (const float*)d_in[3];
    float* out = (float*)d_out;

    if (ws_size >= PACKED_BYTES) {
        float* P = (float*)d_ws;   // packed lower-tri Su
        su_kernel<<<SU_BLOCKS, 256, 0, stream>>>(Lu_raw, P);
        vnngp_kernel<true><<<N_PTS / PTS_PER_BLK, 512, 0, stream>>>(X, Z, mu, P, Lu_raw, out);
    } else {
        vnngp_kernel<false><<<N_PTS / PTS_PER_BLK, 512, 0, stream>>>(X, Z, mu, nullptr, Lu_raw, out);
    }
}

// Round 9
// 182.652 us; speedup vs baseline: 1.3262x; 1.3262x over previous
//
#include <hip/hip_runtime.h>
#include <math.h>

#define N_PTS 65536
#define M_IND 1024
#define KNN 16
#define JITTER 1e-4f

// Packed lower-triangular Su: P[i*(i+1)/2 + j], j <= i.
#define PACKED_FLOATS (M_IND * (M_IND + 1) / 2)               // 524800
#define PACKED_BYTES  ((size_t)PACKED_FLOATS * sizeof(float)) // 2,099,200 B

// ---------------------------------------------------------------------------
// Kernel A: packed Su = tril(Lu Lu^T), Lu = tril(Lu_raw,-1)+diag(exp(diag)).
// R6/R7 variant (best measured of six tried; su-side is implementation-
// invariant ~85us incl. harness overhead, so keep the simplest fast one).
// ---------------------------------------------------------------------------
#define TSU 32
#define SU_BLOCKS 528   // 32*33/2 triangular tiles

__global__ __launch_bounds__(256) void su_kernel(const float* __restrict__ Lu_raw,
                                                 float* __restrict__ P) {
    __shared__ float As[TSU][36];
    __shared__ float Bs[TSU][36];

    int bid = blockIdx.x;
    int rt = (int)((sqrtf(8.0f * (float)bid + 1.0f) - 1.0f) * 0.5f);
    while ((rt + 1) * (rt + 2) / 2 <= bid) ++rt;
    while (rt * (rt + 1) / 2 > bid) --rt;
    int ct = bid - rt * (rt + 1) / 2;   // ct <= rt
    int i0 = rt * TSU, j0 = ct * TSU;

    int tid = threadIdx.x;
    int tx = tid & 15, ty = tid >> 4;
    int sr = tid >> 3, sc = (tid & 7) << 2;
    float a00 = 0.f, a01 = 0.f, a10 = 0.f, a11 = 0.f;

    int nch = ct + 1;                      // k-chunks of 32 (k <= j0+31)
    int gi = i0 + sr, gj = j0 + sr;
    float4 pa = *(const float4*)(Lu_raw + (unsigned)gi * M_IND + sc);
    float4 pb = *(const float4*)(Lu_raw + (unsigned)gj * M_IND + sc);

    for (int c = 0; c < nch; ++c) {
        int gk = (c << 5) + sc;
        float aa[4] = {pa.x, pa.y, pa.z, pa.w};
        float bb[4] = {pb.x, pb.y, pb.z, pb.w};
        #pragma unroll
        for (int q = 0; q < 4; ++q) {
            int k = gk + q;
            aa[q] = (k < gi) ? aa[q] : ((k == gi) ? __expf(aa[q]) : 0.0f);
            bb[q] = (k < gj) ? bb[q] : ((k == gj) ? __expf(bb[q]) : 0.0f);
        }
        *(float4*)&As[sr][sc] = make_float4(aa[0], aa[1], aa[2], aa[3]);
        *(float4*)&Bs[sr][sc] = make_float4(bb[0], bb[1], bb[2], bb[3]);
        __syncthreads();
        if (c + 1 < nch) {
            int kn = ((c + 1) << 5) + sc;
            pa = *(const float4*)(Lu_raw + (unsigned)gi * M_IND + kn);
            pb = *(const float4*)(Lu_raw + (unsigned)gj * M_IND + kn);
        }
        #pragma unroll
        for (int kk = 0; kk < 32; kk += 4) {
            float4 av0 = *(const float4*)&As[ty][kk];
            float4 av1 = *(const float4*)&As[ty + 16][kk];
            float4 bv0 = *(const float4*)&Bs[tx][kk];
            float4 bv1 = *(const float4*)&Bs[tx + 16][kk];
            a00 = fmaf(av0.x, bv0.x, fmaf(av0.y, bv0.y, fmaf(av0.z, bv0.z, fmaf(av0.w, bv0.w, a00))));
            a01 = fmaf(av0.x, bv1.x, fmaf(av0.y, bv1.y, fmaf(av0.z, bv1.z, fmaf(av0.w, bv1.w, a01))));
            a10 = fmaf(av1.x, bv0.x, fmaf(av1.y, bv0.y, fmaf(av1.z, bv0.z, fmaf(av1.w, bv0.w, a10))));
            a11 = fmaf(av1.x, bv1.x, fmaf(av1.y, bv1.y, fmaf(av1.z, bv1.z, fmaf(av1.w, bv1.w, a11))));
        }
        __syncthreads();
    }

    int ia = i0 + ty, ib = i0 + ty + 16;
    int ja = j0 + tx, jb = j0 + tx + 16;
    if (ja <= ia) P[((unsigned)ia * (ia + 1) >> 1) + ja] = a00;
    if (jb <= ia) P[((unsigned)ia * (ia + 1) >> 1) + jb] = a01;
    if (ja <= ib) P[((unsigned)ib * (ib + 1) >> 1) + ja] = a10;
    if (jb <= ib) P[((unsigned)ib * (ib + 1) >> 1) + jb] = a11;
}

// ---------------------------------------------------------------------------
// Sorting-network helpers.
// ---------------------------------------------------------------------------
__device__ __forceinline__ void ce(unsigned long long& x, unsigned long long& y) {
    unsigned long long a = x, b = y;
    bool c = a < b;
    x = c ? a : b;
    y = c ? b : a;
}
__device__ __forceinline__ void ce(float& x, float& y) {
    float a = fminf(x, y), b = fmaxf(x, y);
    x = a; y = b;
}

template <typename KT>
__device__ __forceinline__ void sort16(KT* a) {
    #pragma unroll
    for (int p = 1; p < 16; p <<= 1)
        #pragma unroll
        for (int k = p; k >= 1; k >>= 1)
            #pragma unroll
            for (int j = k & (p - 1); j + k < 16; j += 2 * k)
                #pragma unroll
                for (int i = 0; i < k; ++i)
                    if (i + j + k < 16)
                        if (((i + j) / (2 * p)) == ((i + j + k) / (2 * p)))
                            ce(a[i + j], a[i + j + k]);
}

template <typename KT>
__device__ __forceinline__ void cleanup16(KT* a) {
    #pragma unroll
    for (int d = 8; d >= 1; d >>= 1)
        #pragma unroll
        for (int i = 0; i < 16; ++i)
            if ((i & d) == 0) ce(a[i], a[i | d]);
}

// Identical-bits distance (pass 1, pass 2, read-back, fallback).
__device__ __forceinline__ float distf(float4 z, float x0, float x1, float x2, float xq) {
    float dot = fmaf(x0, z.x, fmaf(x1, z.y, x2 * z.z));
    return fmaxf(fmaf(-2.0f, dot, xq + z.w), 0.0f);
}

// ---------------------------------------------------------------------------
// Kernel B: two-pass threshold selection, 2 POINTS PER THREAD (each Zs read
// feeds two distance computations -> wave-level ds_read count halves; the
// read stream was the binding resource: ~41us of b128 issue at R7's layout).
// 256 threads/block = 64 quads x 4 subs; quad q handles points q and q+64.
// Pass 1: 16 f32 class minima/sub/point, quad shfl-merge -> Tstar(point) =
// 16th of 64 minima (upper bound on true 16th-smallest). Pass 2: collect
// {d <= Tstar} as u16 (cap 16/sub); rebuild exact u64 keys, sort16 + quad
// merge -> exact (dist,idx) top-16. Overflow -> exact serial fallback.
// ---------------------------------------------------------------------------
#define PTS_PER_BLK 128
#define QSTRIDE 17   // u64 per point row (136 B): 4 subs x 16 u16 collect, 16 u64 hand

template <bool USE_WS>
__global__ __launch_bounds__(256, 2) void vnngp_kernel(const float* __restrict__ X,
                                                       const float* __restrict__ Z,
                                                       const float* __restrict__ mu,
                                                       const float* __restrict__ P,
                                                       const float* __restrict__ Lu_raw,
                                                       float* __restrict__ out) {
    __shared__ float4 Zs[M_IND];                             // 16 KB
    __shared__ float mus[M_IND];                             // 4 KB
    __shared__ unsigned long long qb[PTS_PER_BLK * QSTRIDE]; // 17 KB
    int tid = threadIdx.x;
    for (int r = tid; r < M_IND; r += 256) {
        float zx = Z[r * 3 + 0], zy = Z[r * 3 + 1], zz = Z[r * 3 + 2];
        Zs[r] = make_float4(zx, zy, zz, zx * zx + zy * zy + zz * zz);
        mus[r] = mu[r];
    }
    __syncthreads();

    {
        int pt = tid >> 2, sub = tid & 3;     // pt 0..63, quad handles pt & pt+64
        int nA = blockIdx.x * PTS_PER_BLK + pt;
        int nB = nA + 64;
        float xA0 = X[nA * 3 + 0], xA1 = X[nA * 3 + 1], xA2 = X[nA * 3 + 2];
        float xB0 = X[nB * 3 + 0], xB1 = X[nB * 3 + 1], xB2 = X[nB * 3 + 2];
        float xqA = fmaf(xA0, xA0, fmaf(xA1, xA1, xA2 * xA2));
        float xqB = fmaf(xB0, xB0, fmaf(xB1, xB1, xB2 * xB2));
        int mbase = sub << 8;
        int rot = sub << 1;   // subs land on disjoint bank quads

        // ---- Pass 1: 16 interleaved class minima per point (f32) ----
        float TA[16], TB[16];
        #pragma unroll
        for (int j = 0; j < 16; ++j) { TA[j] = 3.4e38f; TB[j] = 3.4e38f; }
        #pragma unroll 1
        for (int c = 0; c < 16; ++c) {
            int base = mbase + (c << 4);
            #pragma unroll
            for (int j = 0; j < 16; ++j) {
                int m = base + ((j + rot) & 15);
                float4 z = Zs[m];
                TA[j] = fminf(TA[j], distf(z, xA0, xA1, xA2, xqA));
                TB[j] = fminf(TB[j], distf(z, xB0, xB1, xB2, xqB));
            }
        }
        sort16(TA);
        sort16(TB);
        #pragma unroll
        for (int round = 1; round <= 2; round <<= 1) {
            float oA[16], oB[16];
            #pragma unroll
            for (int i = 0; i < 16; ++i) {
                oA[i] = __shfl_xor(TA[i], round, 64);
                oB[i] = __shfl_xor(TB[i], round, 64);
            }
            #pragma unroll
            for (int i = 0; i < 16; ++i) {
                TA[i] = fminf(TA[i], oA[15 - i]);
                TB[i] = fminf(TB[i], oB[15 - i]);
            }
            cleanup16(TA);
            cleanup16(TB);
        }
        float TstarA = TA[15], TstarB = TB[15];

        // ---- Pass 2: collect indices with d <= Tstar (u16, cap 16/sub) ----
        unsigned short* mycA = ((unsigned short*)qb) + pt * (QSTRIDE * 4) + sub * 16;
        unsigned short* mycB = ((unsigned short*)qb) + (pt + 64) * (QSTRIDE * 4) + sub * 16;
        int cntA = 0, cntB = 0;
        #pragma unroll 1
        for (int c = 0; c < 16; ++c) {
            int base = mbase + (c << 4);
            #pragma unroll
            for (int j = 0; j < 16; ++j) {
                int m = base + ((j + rot) & 15);
                float4 z = Zs[m];
                float dA = distf(z, xA0, xA1, xA2, xqA);
                float dB = distf(z, xB0, xB1, xB2, xqB);
                if (dA <= TstarA) { if (cntA < 16) mycA[cntA] = (unsigned short)m; ++cntA; }
                if (dB <= TstarB) { if (cntB < 16) mycB[cntB] = (unsigned short)m; ++cntB; }
            }
        }

        int ovfA = cntA > 16 ? 1 : 0;
        ovfA |= __shfl_xor(ovfA, 1, 64);
        ovfA |= __shfl_xor(ovfA, 2, 64);
        int ovfB = cntB > 16 ? 1 : 0;
        ovfB |= __shfl_xor(ovfB, 1, 64);
        ovfB |= __shfl_xor(ovfB, 2, 64);

        // ---- finalize point A ----
        if (!ovfA) {
            const unsigned long long* m64 = (const unsigned long long*)mycA;
            unsigned long long raw[4] = {m64[0], m64[1], m64[2], m64[3]};
            unsigned long long C[16];
            #pragma unroll
            for (int i = 0; i < 16; ++i) {
                int m = (int)((raw[i >> 2] >> ((i & 3) * 16)) & 0x3FF);
                float d = distf(Zs[m], xA0, xA1, xA2, xqA);
                unsigned long long key =
                    ((unsigned long long)__float_as_uint(d) << 32) | (unsigned)m;
                C[i] = (i < cntA) ? key : ~0ULL;
            }
            sort16(C);
            #pragma unroll
            for (int round = 1; round <= 2; round <<= 1) {
                unsigned long long o[16];
                #pragma unroll
                for (int i = 0; i < 16; ++i) o[i] = __shfl_xor(C[i], round, 64);
                #pragma unroll
                for (int i = 0; i < 16; ++i) {
                    unsigned long long b = o[15 - i];
                    C[i] = C[i] < b ? C[i] : b;
                }
                cleanup16(C);
            }
            if (sub == 0) {   // all quad lanes' reads precede (lockstep wave)
                #pragma unroll
                for (int i = 0; i < 16; ++i) qb[pt * QSTRIDE + i] = C[i];
            }
        } else if (sub == 0) {
            unsigned long long R[16];
            #pragma unroll
            for (int i = 0; i < 16; ++i) R[i] = ~0ULL;
            for (int m = 0; m < M_IND; ++m) {
                float d = distf(Zs[m], xA0, xA1, xA2, xqA);
                unsigned long long kk =
                    ((unsigned long long)__float_as_uint(d) << 32) | (unsigned)m;
                if (kk < R[15]) {
                    #pragma unroll
                    for (int j = 0; j < 16; ++j) {
                        unsigned long long t = R[j];
                        bool cc = kk < t;
                        R[j] = cc ? kk : t;
                        kk = cc ? t : kk;
                    }
                }
            }
            #pragma unroll
            for (int i = 0; i < 16; ++i) qb[pt * QSTRIDE + i] = R[i];
        }

        // ---- finalize point B ----
        if (!ovfB) {
            const unsigned long long* m64 = (const unsigned long long*)mycB;
            unsigned long long raw[4] = {m64[0], m64[1], m64[2], m64[3]};
            unsigned long long C[16];
            #pragma unroll
            for (int i = 0; i < 16; ++i) {
                int m = (int)((raw[i >> 2] >> ((i & 3) * 16)) & 0x3FF);
                float d = distf(Zs[m], xB0, xB1, xB2, xqB);
                unsigned long long key =
                    ((unsigned long long)__float_as_uint(d) << 32) | (unsigned)m;
                C[i] = (i < cntB) ? key : ~0ULL;
            }
            sort16(C);
            #pragma unroll
            for (int round = 1; round <= 2; round <<= 1) {
                unsigned long long o[16];
                #pragma unroll
                for (int i = 0; i < 16; ++i) o[i] = __shfl_xor(C[i], round, 64);
                #pragma unroll
                for (int i = 0; i < 16; ++i) {
                    unsigned long long b = o[15 - i];
                    C[i] = C[i] < b ? C[i] : b;
                }
                cleanup16(C);
            }
            if (sub == 0) {
                #pragma unroll
                for (int i = 0; i < 16; ++i) qb[(pt + 64) * QSTRIDE + i] = C[i];
            }
        } else if (sub == 0) {
            unsigned long long R[16];
            #pragma unroll
            for (int i = 0; i < 16; ++i) R[i] = ~0ULL;
            for (int m = 0; m < M_IND; ++m) {
                float d = distf(Zs[m], xB0, xB1, xB2, xqB);
                unsigned long long kk =
                    ((unsigned long long)__float_as_uint(d) << 32) | (unsigned)m;
                if (kk < R[15]) {
                    #pragma unroll
                    for (int j = 0; j < 16; ++j) {
                        unsigned long long t = R[j];
                        bool cc = kk < t;
                        R[j] = cc ? kk : t;
                        kk = cc ? t : kk;
                    }
                }
            }
            #pragma unroll
            for (int i = 0; i < 16; ++i) qb[(pt + 64) * QSTRIDE + i] = R[i];
        }
    }
    __syncthreads();
    if (tid >= PTS_PER_BLK) return;

    // ---- Phase 2: local GP, one thread per point ----
    int n = blockIdx.x * PTS_PER_BLK + tid;
    int idx[KNN];
    float kv[KNN];
    float nx[KNN], ny[KNN], nz[KNN], nq[KNN];
    #pragma unroll
    for (int a = 0; a < KNN; ++a) {
        unsigned long long k = qb[tid * QSTRIDE + a];
        idx[a] = (int)(k & 0xFFFFFFFFULL);
        float d = __uint_as_float((unsigned)(k >> 32));
        kv[a] = __expf(-0.5f * d);            // lKxz entries
        float4 z = Zs[idx[a]];
        nx[a] = z.x; ny[a] = z.y; nz[a] = z.z; nq[a] = z.w;
    }

    // A = lKzz + JITTER*I (lower tri); lKzz diag carries global jitter from
    // Kzz_j = L L^T -> diag = 1 + 2*JITTER.
    float A[KNN * (KNN + 1) / 2];
    #pragma unroll
    for (int r = 0; r < KNN; ++r) {
        A[r * (r + 1) / 2 + r] = 1.0f + 2.0f * JITTER;
        #pragma unroll
        for (int c = 0; c < r; ++c) {
            float dd = nq[r] + nq[c]
                     - 2.0f * (nx[r] * nx[c] + ny[r] * ny[c] + nz[r] * nz[c]);
            dd = fmaxf(dd, 0.0f);
            A[r * (r + 1) / 2 + c] = __expf(-0.5f * dd);
        }
    }

    // In-place Cholesky; store 1/L[c][c] in the diagonal slot.
    #pragma unroll
    for (int c = 0; c < KNN; ++c) {
        float diag = A[c * (c + 1) / 2 + c];
        #pragma unroll
        for (int k = 0; k < c; ++k) {
            float l = A[c * (c + 1) / 2 + k];
            diag = fmaf(-l, l, diag);
        }
        float s = sqrtf(fmaxf(diag, 1e-12f));
        float rinv = 1.0f / s;
        A[c * (c + 1) / 2 + c] = rinv;
        #pragma unroll
        for (int r = c + 1; r < KNN; ++r) {
            float v = A[r * (r + 1) / 2 + c];
            #pragma unroll
            for (int k = 0; k < c; ++k)
                v = fmaf(-A[r * (r + 1) / 2 + k], A[c * (c + 1) / 2 + k], v);
            A[r * (r + 1) / 2 + c] = v * rinv;
        }
    }

    // Solve A w = kv (forward then backward).
    float w[KNN];
    #pragma unroll
    for (int r = 0; r < KNN; ++r) {
        float v = kv[r];
        #pragma unroll
        for (int c = 0; c < r; ++c) v = fmaf(-A[r * (r + 1) / 2 + c], w[c], v);
        w[r] = v * A[r * (r + 1) / 2 + r];
    }
    #pragma unroll
    for (int r = KNN - 1; r >= 0; --r) {
        float v = w[r];
        #pragma unroll
        for (int c = r + 1; c < KNN; ++c) v = fmaf(-A[c * (c + 1) / 2 + r], w[c], v);
        w[r] = v * A[r * (r + 1) / 2 + r];
    }

    // W lKzz W^T = w.k - JITTER*||w||^2   (A w = k, lKzz = A - JITTER*I)
    float wk = 0.f, ww = 0.f, mean = 0.f;
    #pragma unroll
    for (int a = 0; a < KNN; ++a) {
        wk = fmaf(w[a], kv[a], wk);
        ww = fmaf(w[a], w[a], ww);
        mean = fmaf(w[a], mus[idx[a]], mean);
    }

    // qs = w^T Su[idx,idx] w
    float qs = 0.f;
    if (USE_WS) {
        #pragma unroll
        for (int r = 0; r < KNN; ++r) {
            int a = idx[r];
            float wr = w[r];
            float rowacc = 0.f;
            #pragma unroll
            for (int c = 0; c < r; ++c) {
                int b = idx[c];
                int hi = a > b ? a : b;
                int lo = a > b ? b : a;
                rowacc = fmaf(w[c], P[((unsigned)hi * (hi + 1) >> 1) + lo], rowacc);
            }
            qs = fmaf(wr, fmaf(wr, P[((unsigned)a * (a + 1) >> 1) + a], 2.0f * rowacc), qs);
        }
    } else {
        // On-demand fallback: qs = sum_k (sum_a w_a * Lu[idx_a, k])^2
        int si[KNN]; float sw[KNN];
        #pragma unroll
        for (int a = 0; a < KNN; ++a) { si[a] = idx[a]; sw[a] = w[a]; }
        #pragma unroll
        for (int a = 1; a < KNN; ++a) {
            int iv = si[a]; float wv = sw[a];
            int b = a - 1;
            while (b >= 0 && si[b] > iv) { si[b + 1] = si[b]; sw[b + 1] = sw[b]; --b; }
            si[b + 1] = iv; sw[b + 1] = wv;
        }
        int s = 0;
        int kend = si[KNN - 1];
        for (int k = 0; k <= kend; ++k) {
            float v = 0.f;
            if (s < KNN && si[s] == k) {
                v = sw[s] * __expf(Lu_raw[(unsigned)k * M_IND + k]);
                ++s;
            }
            for (int a = s; a < KNN; ++a)
                v = fmaf(sw[a], Lu_raw[(unsigned)si[a] * M_IND + k], v);
            qs = fmaf(v, v, qs);
        }
    }

    float cov = 1.0f - (wk - JITTER * ww) + qs;
    float sd = sqrtf(fmaxf(cov, 0.05f));
    out[n] = mean;
    out[N_PTS + n] = sd;
}

// ---------------------------------------------------------------------------
extern "C" void kernel_launch(void* const* d_in, const int* in_sizes, int n_in,
                              void* d_out, int out_size, void* d_ws, size_t ws_size,
                              hipStream_t stream) {
    const float* X      = (const float*)d_in[0];
    const float* Z      = (const float*)d_in[1];
    const float* Lu_raw = (const float*)d_in[2];
    const float* mu     = (const float*)d_in[3];
    float* out = (float*)d_out;

    if (ws_size >= PACKED_BYTES) {
        float* P = (float*)d_ws;   // packed lower-tri Su
        su_kernel<<<SU_BLOCKS, 256, 0, stream>>>(Lu_raw, P);
        vnngp_kernel<true><<<N_PTS / PTS_PER_BLK, 256, 0, stream>>>(X, Z, mu, P, Lu_raw, out);
    } else {
        vnngp_kernel<false><<<N_PTS / PTS_PER_BLK, 256, 0, stream>>>(X, Z, mu, nullptr, Lu_raw, out);
    }
}

// Round 10
// 172.476 us; speedup vs baseline: 1.4045x; 1.0590x over previous
//
#include <hip/hip_runtime.h>
#include <math.h>

#define N_PTS 65536
#define M_IND 1024
#define KNN 16
#define JITTER 1e-4f

// Packed lower-triangular Su: P[i*(i+1)/2 + j], j <= i.
#define PACKED_FLOATS (M_IND * (M_IND + 1) / 2)               // 524800
#define PACKED_BYTES  ((size_t)PACKED_FLOATS * sizeof(float)) // 2,099,200 B

#define TSU 32
#define SU_BLOCKS 528          // 32*33/2 triangular tiles
#define PTS_PER_BLK 128
#define QSTRIDE 17             // u64 per point row (136 B)
#define GRID_BLKS (N_PTS / PTS_PER_BLK)   // 512

// ---------------------------------------------------------------------------
// One 32x32 Su tile (packed tril(Lu Lu^T)). As/Bs are LDS scratch (32x36 f32
// each); __forceinline__ so addrspace propagates from the caller's __shared__.
// ---------------------------------------------------------------------------
__device__ __forceinline__ void su_tile(const float* __restrict__ Lu_raw,
                                        float* __restrict__ P,
                                        int bid, int tid,
                                        float (*As)[36], float (*Bs)[36]) {
    int rt = (int)((sqrtf(8.0f * (float)bid + 1.0f) - 1.0f) * 0.5f);
    while ((rt + 1) * (rt + 2) / 2 <= bid) ++rt;
    while (rt * (rt + 1) / 2 > bid) --rt;
    int ct = bid - rt * (rt + 1) / 2;   // ct <= rt
    int i0 = rt * TSU, j0 = ct * TSU;

    int tx = tid & 15, ty = tid >> 4;
    int sr = tid >> 3, sc = (tid & 7) << 2;
    float a00 = 0.f, a01 = 0.f, a10 = 0.f, a11 = 0.f;

    int nch = ct + 1;                      // k-chunks of 32 (k <= j0+31)
    int gi = i0 + sr, gj = j0 + sr;
    float4 pa = *(const float4*)(Lu_raw + (unsigned)gi * M_IND + sc);
    float4 pb = *(const float4*)(Lu_raw + (unsigned)gj * M_IND + sc);

    for (int c = 0; c < nch; ++c) {
        int gk = (c << 5) + sc;
        float aa[4] = {pa.x, pa.y, pa.z, pa.w};
        float bb[4] = {pb.x, pb.y, pb.z, pb.w};
        #pragma unroll
        for (int q = 0; q < 4; ++q) {
            int k = gk + q;
            aa[q] = (k < gi) ? aa[q] : ((k == gi) ? __expf(aa[q]) : 0.0f);
            bb[q] = (k < gj) ? bb[q] : ((k == gj) ? __expf(bb[q]) : 0.0f);
        }
        *(float4*)&As[sr][sc] = make_float4(aa[0], aa[1], aa[2], aa[3]);
        *(float4*)&Bs[sr][sc] = make_float4(bb[0], bb[1], bb[2], bb[3]);
        __syncthreads();
        if (c + 1 < nch) {
            int kn = ((c + 1) << 5) + sc;
            pa = *(const float4*)(Lu_raw + (unsigned)gi * M_IND + kn);
            pb = *(const float4*)(Lu_raw + (unsigned)gj * M_IND + kn);
        }
        #pragma unroll
        for (int kk = 0; kk < 32; kk += 4) {
            float4 av0 = *(const float4*)&As[ty][kk];
            float4 av1 = *(const float4*)&As[ty + 16][kk];
            float4 bv0 = *(const float4*)&Bs[tx][kk];
            float4 bv1 = *(const float4*)&Bs[tx + 16][kk];
            a00 = fmaf(av0.x, bv0.x, fmaf(av0.y, bv0.y, fmaf(av0.z, bv0.z, fmaf(av0.w, bv0.w, a00))));
            a01 = fmaf(av0.x, bv1.x, fmaf(av0.y, bv1.y, fmaf(av0.z, bv1.z, fmaf(av0.w, bv1.w, a01))));
            a10 = fmaf(av1.x, bv0.x, fmaf(av1.y, bv0.y, fmaf(av1.z, bv0.z, fmaf(av1.w, bv0.w, a10))));
            a11 = fmaf(av1.x, bv1.x, fmaf(av1.y, bv1.y, fmaf(av1.z, bv1.z, fmaf(av1.w, bv1.w, a11))));
        }
        __syncthreads();
    }

    int ia = i0 + ty, ib = i0 + ty + 16;
    int ja = j0 + tx, jb = j0 + tx + 16;
    if (ja <= ia) P[((unsigned)ia * (ia + 1) >> 1) + ja] = a00;
    if (jb <= ia) P[((unsigned)ia * (ia + 1) >> 1) + jb] = a01;
    if (ja <= ib) P[((unsigned)ib * (ib + 1) >> 1) + ja] = a10;
    if (jb <= ib) P[((unsigned)ib * (ib + 1) >> 1) + jb] = a11;
}

// Standalone su kernel (used only on the non-fused fallback path).
__global__ __launch_bounds__(256) void su_kernel(const float* __restrict__ Lu_raw,
                                                 float* __restrict__ P) {
    __shared__ float As[TSU][36];
    __shared__ float Bs[TSU][36];
    su_tile(Lu_raw, P, blockIdx.x, threadIdx.x, As, Bs);
}

// ---------------------------------------------------------------------------
// Sorting-network helpers.
// ---------------------------------------------------------------------------
__device__ __forceinline__ void ce(unsigned long long& x, unsigned long long& y) {
    unsigned long long a = x, b = y;
    bool c = a < b;
    x = c ? a : b;
    y = c ? b : a;
}
__device__ __forceinline__ void ce(float& x, float& y) {
    float a = fminf(x, y), b = fmaxf(x, y);
    x = a; y = b;
}

template <typename KT>
__device__ __forceinline__ void sort16(KT* a) {
    #pragma unroll
    for (int p = 1; p < 16; p <<= 1)
        #pragma unroll
        for (int k = p; k >= 1; k >>= 1)
            #pragma unroll
            for (int j = k & (p - 1); j + k < 16; j += 2 * k)
                #pragma unroll
                for (int i = 0; i < k; ++i)
                    if (i + j + k < 16)
                        if (((i + j) / (2 * p)) == ((i + j + k) / (2 * p)))
                            ce(a[i + j], a[i + j + k]);
}

template <typename KT>
__device__ __forceinline__ void cleanup16(KT* a) {
    #pragma unroll
    for (int d = 8; d >= 1; d >>= 1)
        #pragma unroll
        for (int i = 0; i < 16; ++i)
            if ((i & d) == 0) ce(a[i], a[i | d]);
}

// Identical-bits distance everywhere.
__device__ __forceinline__ float distf(float4 z, float x0, float x1, float x2, float xq) {
    float dot = fmaf(x0, z.x, fmaf(x1, z.y, x2 * z.z));
    return fmaxf(fmaf(-2.0f, dot, xq + z.w), 0.0f);
}

// ---------------------------------------------------------------------------
// MODE 2: fused (su tiles in-kernel + device-flag sync; needs ws for P+ctr).
// MODE 1: two-kernel path (su_kernel writes P first).
// MODE 0: no-workspace exact fallback (qs recomputed from Lu rows).
// Selection: R9's two-pass threshold scheme, 2 points/thread, 4 subs/point.
// ---------------------------------------------------------------------------
template <int MODE>
__global__ __launch_bounds__(256, 2) void vnngp_kernel(const float* __restrict__ X,
                                                       const float* __restrict__ Z,
                                                       const float* __restrict__ mu,
                                                       float* __restrict__ P,
                                                       const float* __restrict__ Lu_raw,
                                                       unsigned int* __restrict__ ctr,
                                                       float* __restrict__ out) {
    __shared__ __align__(16) char smem[37888];
    float4* Zs = (float4*)smem;                                  // 16 KB
    float* mus = (float*)(smem + 16384);                         // 4 KB
    unsigned long long* qb = (unsigned long long*)(smem + 20480); // 17 KB
    int tid = threadIdx.x;

    for (int r = tid; r < M_IND; r += 256) {
        float zx = Z[r * 3 + 0], zy = Z[r * 3 + 1], zz = Z[r * 3 + 2];
        Zs[r] = make_float4(zx, zy, zz, zx * zx + zy * zy + zz * zz);
        mus[r] = mu[r];
    }

    if (MODE == 2) {
        // ---- in-kernel Su tiles (As/Bs alias the qb region: 9216 <= 17408 B)
        float (*As)[36] = (float (*)[36])(smem + 20480);
        float (*Bs)[36] = (float (*)[36])(smem + 20480 + 4608);
        for (int t = blockIdx.x; t < SU_BLOCKS; t += GRID_BLKS)
            su_tile(Lu_raw, P, t, tid, As, Bs);   // contains __syncthreads
        __syncthreads();                           // all P stores drained (vmcnt)
        if (tid == 0) {
            __threadfence();                       // device-scope release
            atomicAdd(ctr, 1u);
        }
        // qb region free again; Zs/mus writes ordered by su_tile's barriers.
    } else {
        __syncthreads();
    }

    {
        int pt = tid >> 2, sub = tid & 3;     // pt 0..63, quad handles pt & pt+64
        int nA = blockIdx.x * PTS_PER_BLK + pt;
        int nB = nA + 64;
        float xA0 = X[nA * 3 + 0], xA1 = X[nA * 3 + 1], xA2 = X[nA * 3 + 2];
        float xB0 = X[nB * 3 + 0], xB1 = X[nB * 3 + 1], xB2 = X[nB * 3 + 2];
        float xqA = fmaf(xA0, xA0, fmaf(xA1, xA1, xA2 * xA2));
        float xqB = fmaf(xB0, xB0, fmaf(xB1, xB1, xB2 * xB2));
        int mbase = sub << 8;
        int rot = sub << 1;   // subs land on disjoint bank quads

        // ---- Pass 1: 16 interleaved class minima per point (f32) ----
        float TA[16], TB[16];
        #pragma unroll
        for (int j = 0; j < 16; ++j) { TA[j] = 3.4e38f; TB[j] = 3.4e38f; }
        #pragma unroll 1
        for (int c = 0; c < 16; ++c) {
            int base = mbase + (c << 4);
            #pragma unroll
            for (int j = 0; j < 16; ++j) {
                int m = base + ((j + rot) & 15);
                float4 z = Zs[m];
                TA[j] = fminf(TA[j], distf(z, xA0, xA1, xA2, xqA));
                TB[j] = fminf(TB[j], distf(z, xB0, xB1, xB2, xqB));
            }
        }
        sort16(TA);
        sort16(TB);
        #pragma unroll
        for (int round = 1; round <= 2; round <<= 1) {
            float oA[16], oB[16];
            #pragma unroll
            for (int i = 0; i < 16; ++i) {
                oA[i] = __shfl_xor(TA[i], round, 64);
                oB[i] = __shfl_xor(TB[i], round, 64);
            }
            #pragma unroll
            for (int i = 0; i < 16; ++i) {
                TA[i] = fminf(TA[i], oA[15 - i]);
                TB[i] = fminf(TB[i], oB[15 - i]);
            }
            cleanup16(TA);
            cleanup16(TB);
        }
        float TstarA = TA[15], TstarB = TB[15];

        // ---- Pass 2: collect indices with d <= Tstar (u16, cap 16/sub) ----
        unsigned short* mycA = ((unsigned short*)qb) + pt * (QSTRIDE * 4) + sub * 16;
        unsigned short* mycB = ((unsigned short*)qb) + (pt + 64) * (QSTRIDE * 4) + sub * 16;
        int cntA = 0, cntB = 0;
        #pragma unroll 1
        for (int c = 0; c < 16; ++c) {
            int base = mbase + (c << 4);
            #pragma unroll
            for (int j = 0; j < 16; ++j) {
                int m = base + ((j + rot) & 15);
                float4 z = Zs[m];
                float dA = distf(z, xA0, xA1, xA2, xqA);
                float dB = distf(z, xB0, xB1, xB2, xqB);
                if (dA <= TstarA) { if (cntA < 16) mycA[cntA] = (unsigned short)m; ++cntA; }
                if (dB <= TstarB) { if (cntB < 16) mycB[cntB] = (unsigned short)m; ++cntB; }
            }
        }

        int ovfA = cntA > 16 ? 1 : 0;
        ovfA |= __shfl_xor(ovfA, 1, 64);
        ovfA |= __shfl_xor(ovfA, 2, 64);
        int ovfB = cntB > 16 ? 1 : 0;
        ovfB |= __shfl_xor(ovfB, 1, 64);
        ovfB |= __shfl_xor(ovfB, 2, 64);

        // ---- finalize point A ----
        if (!ovfA) {
            const unsigned long long* m64 = (const unsigned long long*)mycA;
            unsigned long long raw[4] = {m64[0], m64[1], m64[2], m64[3]};
            unsigned long long C[16];
            #pragma unroll
            for (int i = 0; i < 16; ++i) {
                int m = (int)((raw[i >> 2] >> ((i & 3) * 16)) & 0x3FF);
                float d = distf(Zs[m], xA0, xA1, xA2, xqA);
                unsigned long long key =
                    ((unsigned long long)__float_as_uint(d) << 32) | (unsigned)m;
                C[i] = (i < cntA) ? key : ~0ULL;
            }
            sort16(C);
            #pragma unroll
            for (int round = 1; round <= 2; round <<= 1) {
                unsigned long long o[16];
                #pragma unroll
                for (int i = 0; i < 16; ++i) o[i] = __shfl_xor(C[i], round, 64);
                #pragma unroll
                for (int i = 0; i < 16; ++i) {
                    unsigned long long b = o[15 - i];
                    C[i] = C[i] < b ? C[i] : b;
                }
                cleanup16(C);
            }
            if (sub == 0) {
                #pragma unroll
                for (int i = 0; i < 16; ++i) qb[pt * QSTRIDE + i] = C[i];
            }
        } else if (sub == 0) {
            unsigned long long R[16];
            #pragma unroll
            for (int i = 0; i < 16; ++i) R[i] = ~0ULL;
            for (int m = 0; m < M_IND; ++m) {
                float d = distf(Zs[m], xA0, xA1, xA2, xqA);
                unsigned long long kk =
                    ((unsigned long long)__float_as_uint(d) << 32) | (unsigned)m;
                if (kk < R[15]) {
                    #pragma unroll
                    for (int j = 0; j < 16; ++j) {
                        unsigned long long t = R[j];
                        bool cc = kk < t;
                        R[j] = cc ? kk : t;
                        kk = cc ? t : kk;
                    }
                }
            }
            #pragma unroll
            for (int i = 0; i < 16; ++i) qb[pt * QSTRIDE + i] = R[i];
        }

        // ---- finalize point B ----
        if (!ovfB) {
            const unsigned long long* m64 = (const unsigned long long*)mycB;
            unsigned long long raw[4] = {m64[0], m64[1], m64[2], m64[3]};
            unsigned long long C[16];
            #pragma unroll
            for (int i = 0; i < 16; ++i) {
                int m = (int)((raw[i >> 2] >> ((i & 3) * 16)) & 0x3FF);
                float d = distf(Zs[m], xB0, xB1, xB2, xqB);
                unsigned long long key =
                    ((unsigned long long)__float_as_uint(d) << 32) | (unsigned)m;
                C[i] = (i < cntB) ? key : ~0ULL;
            }
            sort16(C);
            #pragma unroll
            for (int round = 1; round <= 2; round <<= 1) {
                unsigned long long o[16];
                #pragma unroll
                for (int i = 0; i < 16; ++i) o[i] = __shfl_xor(C[i], round, 64);
                #pragma unroll
                for (int i = 0; i < 16; ++i) {
                    unsigned long long b = o[15 - i];
                    C[i] = C[i] < b ? C[i] : b;
                }
                cleanup16(C);
            }
            if (sub == 0) {
                #pragma unroll
                for (int i = 0; i < 16; ++i) qb[(pt + 64) * QSTRIDE + i] = C[i];
            }
        } else if (sub == 0) {
            unsigned long long R[16];
            #pragma unroll
            for (int i = 0; i < 16; ++i) R[i] = ~0ULL;
            for (int m = 0; m < M_IND; ++m) {
                float d = distf(Zs[m], xB0, xB1, xB2, xqB);
                unsigned long long kk =
                    ((unsigned long long)__float_as_uint(d) << 32) | (unsigned)m;
                if (kk < R[15]) {
                    #pragma unroll
                    for (int j = 0; j < 16; ++j) {
                        unsigned long long t = R[j];
                        bool cc = kk < t;
                        R[j] = cc ? kk : t;
                        kk = cc ? t : kk;
                    }
                }
            }
            #pragma unroll
            for (int i = 0; i < 16; ++i) qb[(pt + 64) * QSTRIDE + i] = R[i];
        }
    }
    __syncthreads();

    if (MODE == 2) {
        // Wait for all blocks' Su tiles (selection above overlapped them).
        if (tid == 0) {
            while (__hip_atomic_load(ctr, __ATOMIC_ACQUIRE, __HIP_MEMORY_SCOPE_AGENT)
                   < (unsigned)GRID_BLKS)
                __builtin_amdgcn_s_sleep(8);
        }
        __syncthreads();
    }
    if (tid >= PTS_PER_BLK) return;

    // ---- Phase 2: local GP, one thread per point ----
    int n = blockIdx.x * PTS_PER_BLK + tid;
    int idx[KNN];
    float kv[KNN];
    float nx[KNN], ny[KNN], nz[KNN], nq[KNN];
    #pragma unroll
    for (int a = 0; a < KNN; ++a) {
        unsigned long long k = qb[tid * QSTRIDE + a];
        idx[a] = (int)(k & 0xFFFFFFFFULL);
        float d = __uint_as_float((unsigned)(k >> 32));
        kv[a] = __expf(-0.5f * d);            // lKxz entries
        float4 z = Zs[idx[a]];
        nx[a] = z.x; ny[a] = z.y; nz[a] = z.z; nq[a] = z.w;
    }

    // A = lKzz + JITTER*I (lower tri); diag = 1 + 2*JITTER (Kzz_j = L L^T).
    float A[KNN * (KNN + 1) / 2];
    #pragma unroll
    for (int r = 0; r < KNN; ++r) {
        A[r * (r + 1) / 2 + r] = 1.0f + 2.0f * JITTER;
        #pragma unroll
        for (int c = 0; c < r; ++c) {
            float dd = nq[r] + nq[c]
                     - 2.0f * (nx[r] * nx[c] + ny[r] * ny[c] + nz[r] * nz[c]);
            dd = fmaxf(dd, 0.0f);
            A[r * (r + 1) / 2 + c] = __expf(-0.5f * dd);
        }
    }

    // In-place Cholesky; store 1/L[c][c] in the diagonal slot.
    #pragma unroll
    for (int c = 0; c < KNN; ++c) {
        float diag = A[c * (c + 1) / 2 + c];
        #pragma unroll
        for (int k = 0; k < c; ++k) {
            float l = A[c * (c + 1) / 2 + k];
            diag = fmaf(-l, l, diag);
        }
        float s = sqrtf(fmaxf(diag, 1e-12f));
        float rinv = 1.0f / s;
        A[c * (c + 1) / 2 + c] = rinv;
        #pragma unroll
        for (int r = c + 1; r < KNN; ++r) {
            float v = A[r * (r + 1) / 2 + c];
            #pragma unroll
            for (int k = 0; k < c; ++k)
                v = fmaf(-A[r * (r + 1) / 2 + k], A[c * (c + 1) / 2 + k], v);
            A[r * (r + 1) / 2 + c] = v * rinv;
        }
    }

    // Solve A w = kv (forward then backward).
    float w[KNN];
    #pragma unroll
    for (int r = 0; r < KNN; ++r) {
        float v = kv[r];
        #pragma unroll
        for (int c = 0; c < r; ++c) v = fmaf(-A[r * (r + 1) / 2 + c], w[c], v);
        w[r] = v * A[r * (r + 1) / 2 + r];
    }
    #pragma unroll
    for (int r = KNN - 1; r >= 0; --r) {
        float v = w[r];
        #pragma unroll
        for (int c = r + 1; c < KNN; ++c) v = fmaf(-A[c * (c + 1) / 2 + r], w[c], v);
        w[r] = v * A[r * (r + 1) / 2 + r];
    }

    // W lKzz W^T = w.k - JITTER*||w||^2   (A w = k, lKzz = A - JITTER*I)
    float wk = 0.f, ww = 0.f, mean = 0.f;
    #pragma unroll
    for (int a = 0; a < KNN; ++a) {
        wk = fmaf(w[a], kv[a], wk);
        ww = fmaf(w[a], w[a], ww);
        mean = fmaf(w[a], mus[idx[a]], mean);
    }

    // qs = w^T Su[idx,idx] w
    float qs = 0.f;
    if (MODE != 0) {
        #pragma unroll
        for (int r = 0; r < KNN; ++r) {
            int a = idx[r];
            float wr = w[r];
            float rowacc = 0.f;
            #pragma unroll
            for (int c = 0; c < r; ++c) {
                int b = idx[c];
                int hi = a > b ? a : b;
                int lo = a > b ? b : a;
                rowacc = fmaf(w[c], P[((unsigned)hi * (hi + 1) >> 1) + lo], rowacc);
            }
            qs = fmaf(wr, fmaf(wr, P[((unsigned)a * (a + 1) >> 1) + a], 2.0f * rowacc), qs);
        }
    } else {
        // On-demand fallback: qs = sum_k (sum_a w_a * Lu[idx_a, k])^2
        int si[KNN]; float sw[KNN];
        #pragma unroll
        for (int a = 0; a < KNN; ++a) { si[a] = idx[a]; sw[a] = w[a]; }
        #pragma unroll
        for (int a = 1; a < KNN; ++a) {
            int iv = si[a]; float wv = sw[a];
            int b = a - 1;
            while (b >= 0 && si[b] > iv) { si[b + 1] = si[b]; sw[b + 1] = sw[b]; --b; }
            si[b + 1] = iv; sw[b + 1] = wv;
        }
        int s = 0;
        int kend = si[KNN - 1];
        for (int k = 0; k <= kend; ++k) {
            float v = 0.f;
            if (s < KNN && si[s] == k) {
                v = sw[s] * __expf(Lu_raw[(unsigned)k * M_IND + k]);
                ++s;
            }
            for (int a = s; a < KNN; ++a)
                v = fmaf(sw[a], Lu_raw[(unsigned)si[a] * M_IND + k], v);
            qs = fmaf(v, v, qs);
        }
    }

    float cov = 1.0f - (wk - JITTER * ww) + qs;
    float sd = sqrtf(fmaxf(cov, 0.05f));
    out[n] = mean;
    out[N_PTS + n] = sd;
}

// ---------------------------------------------------------------------------
extern "C" void kernel_launch(void* const* d_in, const int* in_sizes, int n_in,
                              void* d_out, int out_size, void* d_ws, size_t ws_size,
                              hipStream_t stream) {
    const float* X      = (const float*)d_in[0];
    const float* Z      = (const float*)d_in[1];
    const float* Lu_raw = (const float*)d_in[2];
    const float* mu     = (const float*)d_in[3];
    float* out = (float*)d_out;

    if (ws_size >= PACKED_BYTES + 64) {
        // Fused: P + completion counter live in d_ws.
        float* P = (float*)d_ws;
        unsigned int* ctr = (unsigned int*)((char*)d_ws + PACKED_BYTES);
        hipMemsetAsync(ctr, 0, sizeof(unsigned int), stream);
        vnngp_kernel<2><<<GRID_BLKS, 256, 0, stream>>>(X, Z, mu, P, Lu_raw, ctr, out);
    } else if (ws_size >= PACKED_BYTES) {
        float* P = (float*)d_ws;
        su_kernel<<<SU_BLOCKS, 256, 0, stream>>>(Lu_raw, P);
        vnngp_kernel<1><<<GRID_BLKS, 256, 0, stream>>>(X, Z, mu, P, Lu_raw, nullptr, out);
    } else {
        vnngp_kernel<0><<<GRID_BLKS, 256, 0, stream>>>(X, Z, mu, nullptr, Lu_raw, nullptr, out);
    }
}